// Round 9
// baseline (947.020 us; speedup 1.0000x reference)
//
#include <hip/hip_runtime.h>
#include <hip/hip_bf16.h>
#include <math.h>

#define N_USERS 8000
#define N_ENTITIES 32000
#define EMB 64
#define N_GROUPS 4
#define N_EDGES 200000

// bucketed adjacency
#define UBUCK 250            // 8000 users  / 32 per bucket
#define EBUCK 500            // 32000 ents  / 64 per bucket
#define UCAP 1024            // mean 800,  +8 sigma
#define ECAP 640             // mean 400, +12 sigma
#define BIN_CHUNK 2048

typedef __attribute__((ext_vector_type(8))) __bf16 bf16x8;
typedef __attribute__((ext_vector_type(16))) float f32x16;

static __device__ __forceinline__ float bf2f(unsigned short u) {
    union { unsigned int i; float f; } x; x.i = ((unsigned int)u) << 16; return x.f;
}
static __device__ __forceinline__ unsigned short f2bf(float f) {
    union { float f; unsigned int i; } x; x.f = f;
    return (unsigned short)((x.i + 0x7FFF + ((x.i >> 16) & 1)) >> 16);
}
static __device__ __forceinline__ float u2f(unsigned int u) {
    union { unsigned int i; float f; } x; x.i = u; return x.f;
}

// ---------------------------------------------------------------------------
// Convert user_emb / entity_emb to bf16 tables.
// ---------------------------------------------------------------------------
__global__ __launch_bounds__(256) void convert_tables(
    const float* __restrict__ ue, const float* __restrict__ ee,
    ushort* __restrict__ ueh, ushort* __restrict__ eeh)
{
    int i4 = blockIdx.x * 256 + threadIdx.x;   // float4 units
    if (i4 < 128000) {
        float4 v = ((const float4*)ue)[i4];
        ushort4 o; o.x = f2bf(v.x); o.y = f2bf(v.y); o.z = f2bf(v.z); o.w = f2bf(v.w);
        ((ushort4*)ueh)[i4] = o;
    } else if (i4 < 640000) {
        int j = i4 - 128000;
        float4 v = ((const float4*)ee)[j];
        ushort4 o; o.x = f2bf(v.x); o.y = f2bf(v.y); o.z = f2bf(v.z); o.w = f2bf(v.w);
        ((ushort4*)eeh)[j] = o;
    }
}

// ---------------------------------------------------------------------------
// Destination-bucketed binning, both directions, per group.
// Per block: LDS histogram -> one global atomicAdd per touched bucket to
// reserve a segment -> packed-word writes into fixed-capacity bucket regions.
// word (user dir):  (u & 31) | (v << 5)   bucket = u >> 5
// word (ent  dir):  (v & 63) | (u << 6)   bucket = v >> 6
// ---------------------------------------------------------------------------
__global__ __launch_bounds__(256) void bin_edges(
    const int* __restrict__ ui_index, const int* __restrict__ ei_index,
    int* __restrict__ cnt_u, int* __restrict__ cnt_e,
    int* __restrict__ bin_u, int* __restrict__ bin_e)
{
    int g = blockIdx.y;
    const int* ui = ui_index + (size_t)g * N_EDGES;
    const int* ei = ei_index + (size_t)g * N_EDGES;
    __shared__ int hU[UBUCK], hE[EBUCK], bU[UBUCK], bE[EBUCK];
    int t = threadIdx.x;
    for (int i = t; i < UBUCK; i += 256) hU[i] = 0;
    for (int i = t; i < EBUCK; i += 256) hE[i] = 0;
    __syncthreads();
    int e0 = blockIdx.x * BIN_CHUNK;
    int us[8], vs[8];
    #pragma unroll
    for (int i = 0; i < 8; ++i) {
        int e = e0 + i * 256 + t;
        bool ok = e < N_EDGES;
        us[i] = ok ? ui[e] : -1;
        vs[i] = ok ? ei[e] : 0;
        if (ok) {
            atomicAdd(&hU[us[i] >> 5], 1);
            atomicAdd(&hE[vs[i] >> 6], 1);
        }
    }
    __syncthreads();
    for (int i = t; i < UBUCK; i += 256) {
        int c = hU[i];
        bU[i] = c ? atomicAdd(&cnt_u[g * UBUCK + i], c) : 0;
        hU[i] = 0;
    }
    for (int i = t; i < EBUCK; i += 256) {
        int c = hE[i];
        bE[i] = c ? atomicAdd(&cnt_e[g * EBUCK + i], c) : 0;
        hE[i] = 0;
    }
    __syncthreads();
    #pragma unroll
    for (int i = 0; i < 8; ++i) {
        if (us[i] >= 0) {
            int bu = us[i] >> 5;
            int s = atomicAdd(&hU[bu], 1) + bU[bu];
            bin_u[((size_t)g * UBUCK + bu) * UCAP + s] = (us[i] & 31) | (vs[i] << 5);
            int be = vs[i] >> 6;
            int s2 = atomicAdd(&hE[be], 1) + bE[be];
            bin_e[((size_t)g * EBUCK + be) * ECAP + s2] = (vs[i] & 63) | (us[i] << 6);
        }
    }
}

// ---------------------------------------------------------------------------
// Entity hop0, bucketed: block owns 64 entities; streams its entry list,
// quad-gathers ueh rows (lane = uint2 -> 4 dims), ds_add_f32 into LDS
// accumulators (row stride 65 floats to spread banks), then l2norm -> bf16.
// ---------------------------------------------------------------------------
__global__ __launch_bounds__(256) void agg_entity_b(
    const int* __restrict__ cnt_e, const int* __restrict__ bin_e,
    const ushort* __restrict__ ueh, ushort* __restrict__ ebufh, int gbase)
{
    int gz = blockIdx.y, g = gbase + gz;
    int b = blockIdx.x;
    __shared__ float sum[64 * 65];
    int t = threadIdx.x;
    for (int i = t; i < 64 * 65; i += 256) sum[i] = 0.f;
    __syncthreads();
    int count = cnt_e[g * EBUCK + b];
    const int* bin = bin_e + ((size_t)g * EBUCK + b) * ECAP;
    int w = t >> 6, lane = t & 63, q = lane >> 4, d16 = lane & 15;
    for (int base = w * 4; base < count; base += 16) {
        int idx = base + q;
        int word = idx < count ? bin[idx] : -1;
        if (word >= 0) {
            int d6 = word & 63;
            unsigned src = (unsigned)(word >> 6);
            uint2 r = *(const uint2*)(ueh + (src << 6) + (d16 << 2));
            float* dst = sum + d6 * 65 + (d16 << 2);
            atomicAdd(dst + 0, u2f(r.x << 16));
            atomicAdd(dst + 1, u2f(r.x & 0xFFFF0000u));
            atomicAdd(dst + 2, u2f(r.y << 16));
            atomicAdd(dst + 3, u2f(r.y & 0xFFFF0000u));
        }
    }
    __syncthreads();
    for (int r = w * 16; r < w * 16 + 16; ++r) {
        float v = sum[r * 65 + lane];
        float ss = v * v;
        #pragma unroll
        for (int off = 1; off < 64; off <<= 1) ss += __shfl_xor(ss, off);
        float inv = 1.0f / fmaxf(sqrtf(ss), 1e-12f);
        ebufh[(size_t)gz * N_ENTITIES * EMB + (((size_t)b * 64 + r) << 6) + lane]
            = f2bf(v * inv);
    }
}

// ---------------------------------------------------------------------------
// User hop0+hop1 fused, bucketed: block owns 32 users; per entry gathers BOTH
// eeh and ebufh rows; dual LDS accumulators; acc = norm(A) + norm(B).
// ---------------------------------------------------------------------------
__global__ __launch_bounds__(256) void agg_user_b(
    const int* __restrict__ cnt_u, const int* __restrict__ bin_u,
    const ushort* __restrict__ eeh, const ushort* __restrict__ ebufh,
    float* __restrict__ acc, int gbase)
{
    int gz = blockIdx.y, g = gbase + gz;
    int b = blockIdx.x;
    __shared__ float sumA[32 * 65];
    __shared__ float sumB[32 * 65];
    int t = threadIdx.x;
    for (int i = t; i < 32 * 65; i += 256) { sumA[i] = 0.f; sumB[i] = 0.f; }
    __syncthreads();
    int count = cnt_u[g * UBUCK + b];
    const int* bin = bin_u + ((size_t)g * UBUCK + b) * UCAP;
    const ushort* tabB = ebufh + (size_t)gz * N_ENTITIES * EMB;
    int w = t >> 6, lane = t & 63, q = lane >> 4, d16 = lane & 15;
    for (int base = w * 4; base < count; base += 16) {
        int idx = base + q;
        int word = idx < count ? bin[idx] : -1;
        if (word >= 0) {
            int d5 = word & 31;
            unsigned src = (unsigned)(word >> 5);
            unsigned off = (src << 6) + (d16 << 2);
            uint2 ra = *(const uint2*)(eeh + off);
            uint2 rb = *(const uint2*)(tabB + off);
            float* dA = sumA + d5 * 65 + (d16 << 2);
            atomicAdd(dA + 0, u2f(ra.x << 16));
            atomicAdd(dA + 1, u2f(ra.x & 0xFFFF0000u));
            atomicAdd(dA + 2, u2f(ra.y << 16));
            atomicAdd(dA + 3, u2f(ra.y & 0xFFFF0000u));
            float* dB = sumB + d5 * 65 + (d16 << 2);
            atomicAdd(dB + 0, u2f(rb.x << 16));
            atomicAdd(dB + 1, u2f(rb.x & 0xFFFF0000u));
            atomicAdd(dB + 2, u2f(rb.y << 16));
            atomicAdd(dB + 3, u2f(rb.y & 0xFFFF0000u));
        }
    }
    __syncthreads();
    for (int r = w * 8; r < w * 8 + 8; ++r) {
        float a = sumA[r * 65 + lane];
        float bb = sumB[r * 65 + lane];
        float ssA = a * a, ssB = bb * bb;
        #pragma unroll
        for (int off = 1; off < 64; off <<= 1) {
            ssA += __shfl_xor(ssA, off);
            ssB += __shfl_xor(ssB, off);
        }
        float invA = 1.0f / fmaxf(sqrtf(ssA), 1e-12f);
        float invB = 1.0f / fmaxf(sqrtf(ssB), 1e-12f);
        acc[(size_t)g * N_USERS * EMB + (((size_t)b * 32 + r) << 6) + lane]
            = a * invA + bb * invB;
    }
}

// ---------------------------------------------------------------------------
// Fused: attention-combine -> out_user; proj+normalize of (uie, out_user)
// -> bf16 p1h/p2h; diag = 2*dot(n0,n1).
// ---------------------------------------------------------------------------
__global__ __launch_bounds__(256) void combine_proj(
    const float* __restrict__ acc, const float* __restrict__ uie,
    const float* __restrict__ uemb,
    const float* __restrict__ W1, const float* __restrict__ b1,
    const float* __restrict__ W2, const float* __restrict__ b2,
    float* __restrict__ out_user,
    ushort* __restrict__ p1h, ushort* __restrict__ p2h,
    float* __restrict__ diag)
{
    __shared__ float W1s[EMB * EMB];
    __shared__ float W2s[EMB * EMB];
    __shared__ float zs[4][2][EMB];
    __shared__ float hs[4][2][EMB];
    int t = threadIdx.x;
    for (int i = t; i < EMB * EMB; i += 256) { W1s[i] = W1[i]; W2s[i] = W2[i]; }
    int w = t >> 6, lane = t & 63;
    int u = blockIdx.x * 4 + w;

    float ue = uie[(u << 6) + lane];
    float av[N_GROUPS], s[N_GROUPS];
    #pragma unroll
    for (int g = 0; g < N_GROUPS; ++g) {
        av[g] = acc[(size_t)g * N_USERS * EMB + (u << 6) + lane];
        float p = av[g] * ue;
        #pragma unroll
        for (int off = 1; off < 64; off <<= 1) p += __shfl_xor(p, off);
        s[g] = p;
    }
    float m = fmaxf(fmaxf(s[0], s[1]), fmaxf(s[2], s[3]));
    float att[N_GROUPS], tot = 0.f;
    #pragma unroll
    for (int g = 0; g < N_GROUPS; ++g) { att[g] = __expf(s[g] - m); tot += att[g]; }
    float inv = 1.0f / tot;
    float o = uemb[(u << 6) + lane];
    #pragma unroll
    for (int g = 0; g < N_GROUPS; ++g) o += att[g] * inv * av[g];
    out_user[(u << 6) + lane] = o;

    zs[w][0][lane] = ue;
    zs[w][1][lane] = o;
    __syncthreads();
    float h0 = b1[lane], h1 = b1[lane];
    #pragma unroll
    for (int k = 0; k < EMB; ++k) {
        float w1 = W1s[k * EMB + lane];
        h0 = fmaf(zs[w][0][k], w1, h0);
        h1 = fmaf(zs[w][1][k], w1, h1);
    }
    h0 = h0 > 0.f ? h0 : expm1f(h0);
    h1 = h1 > 0.f ? h1 : expm1f(h1);
    hs[w][0][lane] = h0;
    hs[w][1][lane] = h1;
    __syncthreads();
    float y0 = b2[lane], y1 = b2[lane];
    #pragma unroll
    for (int k = 0; k < EMB; ++k) {
        float w2 = W2s[k * EMB + lane];
        y0 = fmaf(hs[w][0][k], w2, y0);
        y1 = fmaf(hs[w][1][k], w2, y1);
    }
    float ss0 = y0 * y0, ss1 = y1 * y1;
    #pragma unroll
    for (int off = 1; off < 64; off <<= 1) {
        ss0 += __shfl_xor(ss0, off);
        ss1 += __shfl_xor(ss1, off);
    }
    float n0 = y0 / fmaxf(sqrtf(ss0), 1e-12f);
    float n1 = y1 / fmaxf(sqrtf(ss1), 1e-12f);
    p1h[(u << 6) + lane] = f2bf(n0);
    p2h[(u << 6) + lane] = f2bf(n1);
    float d = n0 * n1;
    #pragma unroll
    for (int off = 1; off < 64; off <<= 1) d += __shfl_xor(d, off);
    if (lane == 0) diag[u] = d * 2.0f;
}

// ---------------------------------------------------------------------------
// MFMA LSE: one traversal of logits = 2 * A@B^T -> row & col exp-sum partials.
// ---------------------------------------------------------------------------
#define NCHUNK 25
#define TILES_PER_CHUNK 10
#define NWAVES (250 * NCHUNK)
__global__ __launch_bounds__(256) void lse_mfma(
    const ushort* __restrict__ Ah, const ushort* __restrict__ Bh,
    float* __restrict__ rowp, float* __restrict__ colp)
{
    int W = blockIdx.x * 4 + (threadIdx.x >> 6);
    if (W >= NWAVES) return;
    int lane = threadIdx.x & 63;
    int strip = W / NCHUNK;
    int chunk = W % NCHUNK;
    int i0 = strip * 32;
    int hl = lane >> 5;
    int l31 = lane & 31;

    const bf16x8* A8 = (const bf16x8*)Ah;
    const bf16x8* B8 = (const bf16x8*)Bh;

    bf16x8 afrag[4];
    #pragma unroll
    for (int m = 0; m < 4; ++m)
        afrag[m] = A8[(i0 + l31) * 8 + m * 2 + hl];

    float rowacc[16];
    #pragma unroll
    for (int r = 0; r < 16; ++r) rowacc[r] = 0.f;

    for (int tj = 0; tj < TILES_PER_CHUNK; ++tj) {
        int j0 = chunk * (TILES_PER_CHUNK * 32) + tj * 32;
        bf16x8 bfrag[4];
        #pragma unroll
        for (int m = 0; m < 4; ++m)
            bfrag[m] = B8[(j0 + l31) * 8 + m * 2 + hl];
        f32x16 acc;
        #pragma unroll
        for (int r = 0; r < 16; ++r) acc[r] = 0.f;
        #pragma unroll
        for (int m = 0; m < 4; ++m)
            acc = __builtin_amdgcn_mfma_f32_32x32x16_bf16(afrag[m], bfrag[m], acc, 0, 0, 0);
        float csum = 0.f;
        #pragma unroll
        for (int r = 0; r < 16; ++r) {
            float e = __expf(acc[r] * 2.0f);
            rowacc[r] += e;
            csum += e;
        }
        csum += __shfl_xor(csum, 32);
        if (lane < 32) colp[strip * 8000 + j0 + lane] = csum;
    }
    #pragma unroll
    for (int r = 0; r < 16; ++r) {
        float v = rowacc[r];
        #pragma unroll
        for (int off = 1; off < 32; off <<= 1) v += __shfl_xor(v, off);
        if (l31 == 0)
            rowp[chunk * 8000 + i0 + (r & 3) + 8 * (r >> 2) + 4 * hl] = v;
    }
}

// ---------------------------------------------------------------------------
// se_row[i] = sum_c rowp[c][i]; se_col[j] = sum_s colp[s][j]
// ---------------------------------------------------------------------------
__global__ __launch_bounds__(256) void reduce_partials(
    const float* __restrict__ rowp, const float* __restrict__ colp,
    float* __restrict__ se_row, float* __restrict__ se_col)
{
    int id = blockIdx.x * 256 + threadIdx.x;
    if (id < N_USERS) {
        float s = 0.f;
        for (int c = 0; c < NCHUNK; ++c) s += rowp[c * 8000 + id];
        se_row[id] = s;
    } else if (id < 2 * N_USERS) {
        int j = id - N_USERS;
        float s = 0.f;
        for (int st = 0; st < 250; ++st) s += colp[st * 8000 + j];
        se_col[j] = s;
    }
}

// ---------------------------------------------------------------------------
// loss = mean_i( 0.5*(log(se_row)+log(se_col)) - diag )
// ---------------------------------------------------------------------------
__global__ __launch_bounds__(256) void loss_kernel(
    const float* __restrict__ se_row, const float* __restrict__ se_col,
    const float* __restrict__ diag, float* __restrict__ out)
{
    __shared__ float red[256];
    int t = threadIdx.x;
    float s = 0.f;
    for (int i = t; i < N_USERS; i += 256)
        s += 0.5f * (logf(se_row[i]) + logf(se_col[i])) - diag[i];
    red[t] = s;
    __syncthreads();
    for (int w = 128; w > 0; w >>= 1) {
        if (t < w) red[t] += red[t + w];
        __syncthreads();
    }
    if (t == 0) out[0] = red[0] / (float)N_USERS;
}

extern "C" void kernel_launch(void* const* d_in, const int* in_sizes, int n_in,
                              void* d_out, int out_size, void* d_ws, size_t ws_size,
                              hipStream_t stream)
{
    const float* user_emb   = (const float*)d_in[0];
    const float* user_ui    = (const float*)d_in[1];
    const float* entity_emb = (const float*)d_in[2];
    const float* W1 = (const float*)d_in[3];
    const float* b1 = (const float*)d_in[4];
    const float* W2 = (const float*)d_in[5];
    const float* b2 = (const float*)d_in[6];
    const int* ui_index = (const int*)d_in[7];
    const int* ei_index = (const int*)d_in[8];

    float* ws = (float*)d_ws;
    // Layout (float units). Lifetimes stream-ordered; overlays noted.
    float* acc    = ws;                        // [0, 2,048,000) dead after combine_proj
    float* colp   = acc;                       //   overlay: lse col partials (2,000,000)
    float* se_row = ws + 2048000;              // 8,000
    float* se_col = se_row + 8000;             // 8,000
    float* diag   = se_col + 8000;             // 8,000  (ends 2,072,000)
    ushort* p1h = (ushort*)(ws + 2072000);     // 512,000 ushort -> [2,072,000, 2,328,000)
    ushort* p2h = (ushort*)(ws + 2328000);     // 512,000 ushort -> [2,328,000, 2,584,000)
    float* rowp = ws + 2584000;                // 200,000 -> ends 2,784,000
    int* cnt_u = (int*)(ws + 2784000);         // 4*250 = 1,000
    int* cnt_e = cnt_u + N_GROUPS * UBUCK;     // 4*500 = 2,000 (ends 2,787,000)
    int* bin_u = cnt_e + N_GROUPS * EBUCK;     // 4*250*1024 = 1,024,000 (ends 3,811,000)
    int* bin_e = bin_u + N_GROUPS * UBUCK * UCAP; // 4*500*640 = 1,280,000 (ends 5,091,000)
    ushort* ueh = (ushort*)(ws + 5091000);     // 512,000 ushort (256,000 f)
    ushort* eeh = (ushort*)(ws + 5347000);     // 2,048,000 ushort (ends 6,371,000)
    ushort* ebufh = (ushort*)(ws + 6371000);   // nG * 2,048,000 ushort

    const size_t BASE_F = 6371000;
    int nG = 1;
    if (ws_size >= (BASE_F + 4 * 1024000) * 4) nG = 4;       // 41.9 MB
    else if (ws_size >= (BASE_F + 2 * 1024000) * 4) nG = 2;  // 33.7 MB

    float* out_user = (float*)d_out;           // 512,000
    float* out_loss = out_user + 512000;       // 1

    dim3 b256(256);

    hipMemsetAsync(cnt_u, 0, (size_t)N_GROUPS * (UBUCK + EBUCK) * 4, stream);
    convert_tables<<<2500, b256, 0, stream>>>(user_emb, entity_emb, ueh, eeh);
    bin_edges<<<dim3((N_EDGES + BIN_CHUNK - 1) / BIN_CHUNK, N_GROUPS), b256, 0, stream>>>(
        ui_index, ei_index, cnt_u, cnt_e, bin_u, bin_e);

    for (int gbase = 0; gbase < N_GROUPS; gbase += nG) {
        agg_entity_b<<<dim3(EBUCK, nG), b256, 0, stream>>>(
            cnt_e, bin_e, ueh, ebufh, gbase);
        agg_user_b<<<dim3(UBUCK, nG), b256, 0, stream>>>(
            cnt_u, bin_u, eeh, ebufh, acc, gbase);
    }

    combine_proj<<<N_USERS / 4, b256, 0, stream>>>(
        acc, user_ui, user_emb, W1, b1, W2, b2,
        out_user, p1h, p2h, diag);

    lse_mfma<<<(NWAVES + 3) / 4, b256, 0, stream>>>(p1h, p2h, rowp, colp);
    reduce_partials<<<(2 * N_USERS + 255) / 256, b256, 0, stream>>>(
        rowp, colp, se_row, se_col);
    loss_kernel<<<1, b256, 0, stream>>>(se_row, se_col, diag, out_loss);
}

// Round 10
// 194.422 us; speedup vs baseline: 4.8710x; 4.8710x over previous
//
#include <hip/hip_runtime.h>
#include <hip/hip_bf16.h>
#include <math.h>

#define N_USERS 8000
#define N_ENTITIES 32000
#define EMB 64
#define N_GROUPS 4
#define N_EDGES 200000

// bucketed adjacency
#define UBUCK 250            // 8000 users  / 32 per bucket
#define EBUCK 500            // 32000 ents  / 64 per bucket
#define UCAP 1024            // mean 800,  +8 sigma
#define ECAP 640             // mean 400, +12 sigma
#define BIN_CHUNK 2048

typedef __attribute__((ext_vector_type(8))) __bf16 bf16x8;
typedef __attribute__((ext_vector_type(16))) float f32x16;

static __device__ __forceinline__ float bf2f(unsigned short u) {
    union { unsigned int i; float f; } x; x.i = ((unsigned int)u) << 16; return x.f;
}
static __device__ __forceinline__ unsigned short f2bf(float f) {
    union { float f; unsigned int i; } x; x.f = f;
    return (unsigned short)((x.i + 0x7FFF + ((x.i >> 16) & 1)) >> 16);
}
static __device__ __forceinline__ float u2f(unsigned int u) {
    union { unsigned int i; float f; } x; x.i = u; return x.f;
}

// ---------------------------------------------------------------------------
// Convert user_emb / entity_emb to bf16 tables.
// ---------------------------------------------------------------------------
__global__ __launch_bounds__(256) void convert_tables(
    const float* __restrict__ ue, const float* __restrict__ ee,
    ushort* __restrict__ ueh, ushort* __restrict__ eeh)
{
    int i4 = blockIdx.x * 256 + threadIdx.x;   // float4 units
    if (i4 < 128000) {
        float4 v = ((const float4*)ue)[i4];
        ushort4 o; o.x = f2bf(v.x); o.y = f2bf(v.y); o.z = f2bf(v.z); o.w = f2bf(v.w);
        ((ushort4*)ueh)[i4] = o;
    } else if (i4 < 640000) {
        int j = i4 - 128000;
        float4 v = ((const float4*)ee)[j];
        ushort4 o; o.x = f2bf(v.x); o.y = f2bf(v.y); o.z = f2bf(v.z); o.w = f2bf(v.w);
        ((ushort4*)eeh)[j] = o;
    }
}

// ---------------------------------------------------------------------------
// Destination-bucketed binning, both directions, per group.
// word (user dir):  (u & 31) | (v << 5)   bucket = u >> 5
// word (ent  dir):  (v & 63) | (u << 6)   bucket = v >> 6
// Only int atomics: LDS histogram + one global atomicAdd per (block,bucket).
// ---------------------------------------------------------------------------
__global__ __launch_bounds__(256) void bin_edges(
    const int* __restrict__ ui_index, const int* __restrict__ ei_index,
    int* __restrict__ cnt_u, int* __restrict__ cnt_e,
    int* __restrict__ bin_u, int* __restrict__ bin_e)
{
    int g = blockIdx.y;
    const int* ui = ui_index + (size_t)g * N_EDGES;
    const int* ei = ei_index + (size_t)g * N_EDGES;
    __shared__ int hU[UBUCK], hE[EBUCK], bU[UBUCK], bE[EBUCK];
    int t = threadIdx.x;
    for (int i = t; i < UBUCK; i += 256) hU[i] = 0;
    for (int i = t; i < EBUCK; i += 256) hE[i] = 0;
    __syncthreads();
    int e0 = blockIdx.x * BIN_CHUNK;
    int us[8], vs[8];
    #pragma unroll
    for (int i = 0; i < 8; ++i) {
        int e = e0 + i * 256 + t;
        bool ok = e < N_EDGES;
        us[i] = ok ? ui[e] : -1;
        vs[i] = ok ? ei[e] : 0;
        if (ok) {
            atomicAdd(&hU[us[i] >> 5], 1);
            atomicAdd(&hE[vs[i] >> 6], 1);
        }
    }
    __syncthreads();
    for (int i = t; i < UBUCK; i += 256) {
        int c = hU[i];
        bU[i] = c ? atomicAdd(&cnt_u[g * UBUCK + i], c) : 0;
        hU[i] = 0;
    }
    for (int i = t; i < EBUCK; i += 256) {
        int c = hE[i];
        bE[i] = c ? atomicAdd(&cnt_e[g * EBUCK + i], c) : 0;
        hE[i] = 0;
    }
    __syncthreads();
    #pragma unroll
    for (int i = 0; i < 8; ++i) {
        if (us[i] >= 0) {
            int bu = us[i] >> 5;
            int s = atomicAdd(&hU[bu], 1) + bU[bu];
            if (s < UCAP)
                bin_u[((size_t)g * UBUCK + bu) * UCAP + s] = (us[i] & 31) | (vs[i] << 5);
            int be = vs[i] >> 6;
            int s2 = atomicAdd(&hE[be], 1) + bE[be];
            if (s2 < ECAP)
                bin_e[((size_t)g * EBUCK + be) * ECAP + s2] = (vs[i] & 63) | (us[i] << 6);
        }
    }
}

// ---------------------------------------------------------------------------
// Entity hop0, bucketed: counting-sort the bucket's entries in LDS (int
// atomics only), then per destination row: quad-slot register accumulation
// (4 edge slots x 16 dim-lanes, uint2 = 4 bf16 dims/lane), cross-slot
// shfl_xor reduce, l2norm, bf16 store. No fp32 atomics anywhere.
// ---------------------------------------------------------------------------
__global__ __launch_bounds__(256) void agg_entity_b(
    const int* __restrict__ cnt_e, const int* __restrict__ bin_e,
    const ushort* __restrict__ ueh, ushort* __restrict__ ebufh, int gbase)
{
    int gz = blockIdx.y, g = gbase + gz;
    int b = blockIdx.x;
    __shared__ int wds[ECAP];
    __shared__ int srt[ECAP];
    __shared__ int cnt[64];
    __shared__ int ptr[65];
    __shared__ int cur[64];
    int t = threadIdx.x;
    int count = min(cnt_e[g * EBUCK + b], ECAP);
    const int* bin = bin_e + ((size_t)g * EBUCK + b) * ECAP;
    if (t < 64) cnt[t] = 0;
    __syncthreads();
    for (int i = t; i < count; i += 256) {
        int w_ = bin[i];
        wds[i] = w_;
        atomicAdd(&cnt[w_ & 63], 1);
    }
    __syncthreads();
    if (t == 0) {
        int run = 0;
        for (int i = 0; i < 64; ++i) { ptr[i] = run; run += cnt[i]; }
        ptr[64] = run;
    }
    __syncthreads();
    if (t < 64) cur[t] = ptr[t];
    __syncthreads();
    for (int i = t; i < count; i += 256) {
        int w_ = wds[i];
        int pos = atomicAdd(&cur[w_ & 63], 1);
        srt[pos] = w_ >> 6;
    }
    __syncthreads();
    int wv = t >> 6, lane = t & 63, q = lane >> 4, d16 = lane & 15;
    for (int r = wv; r < 64; r += 4) {
        int start = ptr[r], end = ptr[r + 1];
        float a0 = 0.f, a1 = 0.f, a2 = 0.f, a3 = 0.f;
        for (int base = start; base < end; base += 4) {
            int idx = base + q;
            int src = idx < end ? srt[idx] : -1;
            unsigned sidx = src >= 0 ? (unsigned)src : 0u;
            uint2 r2 = *(const uint2*)(ueh + (sidx << 6) + (d16 << 2));
            if (src < 0) { r2.x = 0u; r2.y = 0u; }
            a0 += u2f(r2.x << 16);
            a1 += u2f(r2.x & 0xFFFF0000u);
            a2 += u2f(r2.y << 16);
            a3 += u2f(r2.y & 0xFFFF0000u);
        }
        a0 += __shfl_xor(a0, 16); a0 += __shfl_xor(a0, 32);
        a1 += __shfl_xor(a1, 16); a1 += __shfl_xor(a1, 32);
        a2 += __shfl_xor(a2, 16); a2 += __shfl_xor(a2, 32);
        a3 += __shfl_xor(a3, 16); a3 += __shfl_xor(a3, 32);
        float ss = a0 * a0 + a1 * a1 + a2 * a2 + a3 * a3;
        #pragma unroll
        for (int off = 1; off < 16; off <<= 1) ss += __shfl_xor(ss, off);
        float inv = 1.0f / fmaxf(sqrtf(ss), 1e-12f);
        if (lane < 16) {
            ushort4 o;
            o.x = f2bf(a0 * inv); o.y = f2bf(a1 * inv);
            o.z = f2bf(a2 * inv); o.w = f2bf(a3 * inv);
            *(ushort4*)(ebufh + (size_t)gz * N_ENTITIES * EMB
                        + (((size_t)b * 64 + r) << 6) + (d16 << 2)) = o;
        }
    }
}

// ---------------------------------------------------------------------------
// User hop0+hop1 fused, bucketed: same counting-sort, then per row gather
// BOTH eeh and ebufh rows per edge slot; acc = norm(A) + norm(B).
// ---------------------------------------------------------------------------
__global__ __launch_bounds__(256) void agg_user_b(
    const int* __restrict__ cnt_u, const int* __restrict__ bin_u,
    const ushort* __restrict__ eeh, const ushort* __restrict__ ebufh,
    float* __restrict__ acc, int gbase)
{
    int gz = blockIdx.y, g = gbase + gz;
    int b = blockIdx.x;
    __shared__ int wds[UCAP];
    __shared__ int srt[UCAP];
    __shared__ int cnt[32];
    __shared__ int ptr[33];
    __shared__ int cur[32];
    int t = threadIdx.x;
    int count = min(cnt_u[g * UBUCK + b], UCAP);
    const int* bin = bin_u + ((size_t)g * UBUCK + b) * UCAP;
    const ushort* tabB = ebufh + (size_t)gz * N_ENTITIES * EMB;
    if (t < 32) cnt[t] = 0;
    __syncthreads();
    for (int i = t; i < count; i += 256) {
        int w_ = bin[i];
        wds[i] = w_;
        atomicAdd(&cnt[w_ & 31], 1);
    }
    __syncthreads();
    if (t == 0) {
        int run = 0;
        for (int i = 0; i < 32; ++i) { ptr[i] = run; run += cnt[i]; }
        ptr[32] = run;
    }
    __syncthreads();
    if (t < 32) cur[t] = ptr[t];
    __syncthreads();
    for (int i = t; i < count; i += 256) {
        int w_ = wds[i];
        int pos = atomicAdd(&cur[w_ & 31], 1);
        srt[pos] = w_ >> 5;
    }
    __syncthreads();
    int wv = t >> 6, lane = t & 63, q = lane >> 4, d16 = lane & 15;
    for (int r = wv; r < 32; r += 4) {
        int start = ptr[r], end = ptr[r + 1];
        float a0 = 0.f, a1 = 0.f, a2 = 0.f, a3 = 0.f;
        float b0 = 0.f, b1_ = 0.f, b2_ = 0.f, b3 = 0.f;
        for (int base = start; base < end; base += 4) {
            int idx = base + q;
            int src = idx < end ? srt[idx] : -1;
            unsigned sidx = src >= 0 ? (unsigned)src : 0u;
            unsigned off = (sidx << 6) + (d16 << 2);
            uint2 ra = *(const uint2*)(eeh + off);
            uint2 rb = *(const uint2*)(tabB + off);
            if (src < 0) { ra.x = 0u; ra.y = 0u; rb.x = 0u; rb.y = 0u; }
            a0 += u2f(ra.x << 16);
            a1 += u2f(ra.x & 0xFFFF0000u);
            a2 += u2f(ra.y << 16);
            a3 += u2f(ra.y & 0xFFFF0000u);
            b0  += u2f(rb.x << 16);
            b1_ += u2f(rb.x & 0xFFFF0000u);
            b2_ += u2f(rb.y << 16);
            b3  += u2f(rb.y & 0xFFFF0000u);
        }
        a0 += __shfl_xor(a0, 16); a0 += __shfl_xor(a0, 32);
        a1 += __shfl_xor(a1, 16); a1 += __shfl_xor(a1, 32);
        a2 += __shfl_xor(a2, 16); a2 += __shfl_xor(a2, 32);
        a3 += __shfl_xor(a3, 16); a3 += __shfl_xor(a3, 32);
        b0  += __shfl_xor(b0, 16);  b0  += __shfl_xor(b0, 32);
        b1_ += __shfl_xor(b1_, 16); b1_ += __shfl_xor(b1_, 32);
        b2_ += __shfl_xor(b2_, 16); b2_ += __shfl_xor(b2_, 32);
        b3  += __shfl_xor(b3, 16);  b3  += __shfl_xor(b3, 32);
        float ssA = a0 * a0 + a1 * a1 + a2 * a2 + a3 * a3;
        float ssB = b0 * b0 + b1_ * b1_ + b2_ * b2_ + b3 * b3;
        #pragma unroll
        for (int off = 1; off < 16; off <<= 1) {
            ssA += __shfl_xor(ssA, off);
            ssB += __shfl_xor(ssB, off);
        }
        float invA = 1.0f / fmaxf(sqrtf(ssA), 1e-12f);
        float invB = 1.0f / fmaxf(sqrtf(ssB), 1e-12f);
        if (lane < 16) {
            float4 o;
            o.x = a0 * invA + b0 * invB;
            o.y = a1 * invA + b1_ * invB;
            o.z = a2 * invA + b2_ * invB;
            o.w = a3 * invA + b3 * invB;
            *(float4*)(acc + (size_t)g * N_USERS * EMB
                       + (((size_t)b * 32 + r) << 6) + (d16 << 2)) = o;
        }
    }
}

// ---------------------------------------------------------------------------
// Fused: attention-combine -> out_user; proj+normalize of (uie, out_user)
// -> bf16 p1h/p2h; diag = 2*dot(n0,n1).
// ---------------------------------------------------------------------------
__global__ __launch_bounds__(256) void combine_proj(
    const float* __restrict__ acc, const float* __restrict__ uie,
    const float* __restrict__ uemb,
    const float* __restrict__ W1, const float* __restrict__ b1,
    const float* __restrict__ W2, const float* __restrict__ b2,
    float* __restrict__ out_user,
    ushort* __restrict__ p1h, ushort* __restrict__ p2h,
    float* __restrict__ diag)
{
    __shared__ float W1s[EMB * EMB];
    __shared__ float W2s[EMB * EMB];
    __shared__ float zs[4][2][EMB];
    __shared__ float hs[4][2][EMB];
    int t = threadIdx.x;
    for (int i = t; i < EMB * EMB; i += 256) { W1s[i] = W1[i]; W2s[i] = W2[i]; }
    int w = t >> 6, lane = t & 63;
    int u = blockIdx.x * 4 + w;

    float ue = uie[(u << 6) + lane];
    float av[N_GROUPS], s[N_GROUPS];
    #pragma unroll
    for (int g = 0; g < N_GROUPS; ++g) {
        av[g] = acc[(size_t)g * N_USERS * EMB + (u << 6) + lane];
        float p = av[g] * ue;
        #pragma unroll
        for (int off = 1; off < 64; off <<= 1) p += __shfl_xor(p, off);
        s[g] = p;
    }
    float m = fmaxf(fmaxf(s[0], s[1]), fmaxf(s[2], s[3]));
    float att[N_GROUPS], tot = 0.f;
    #pragma unroll
    for (int g = 0; g < N_GROUPS; ++g) { att[g] = __expf(s[g] - m); tot += att[g]; }
    float inv = 1.0f / tot;
    float o = uemb[(u << 6) + lane];
    #pragma unroll
    for (int g = 0; g < N_GROUPS; ++g) o += att[g] * inv * av[g];
    out_user[(u << 6) + lane] = o;

    zs[w][0][lane] = ue;
    zs[w][1][lane] = o;
    __syncthreads();
    float h0 = b1[lane], h1 = b1[lane];
    #pragma unroll
    for (int k = 0; k < EMB; ++k) {
        float w1 = W1s[k * EMB + lane];
        h0 = fmaf(zs[w][0][k], w1, h0);
        h1 = fmaf(zs[w][1][k], w1, h1);
    }
    h0 = h0 > 0.f ? h0 : expm1f(h0);
    h1 = h1 > 0.f ? h1 : expm1f(h1);
    hs[w][0][lane] = h0;
    hs[w][1][lane] = h1;
    __syncthreads();
    float y0 = b2[lane], y1 = b2[lane];
    #pragma unroll
    for (int k = 0; k < EMB; ++k) {
        float w2 = W2s[k * EMB + lane];
        y0 = fmaf(hs[w][0][k], w2, y0);
        y1 = fmaf(hs[w][1][k], w2, y1);
    }
    float ss0 = y0 * y0, ss1 = y1 * y1;
    #pragma unroll
    for (int off = 1; off < 64; off <<= 1) {
        ss0 += __shfl_xor(ss0, off);
        ss1 += __shfl_xor(ss1, off);
    }
    float n0 = y0 / fmaxf(sqrtf(ss0), 1e-12f);
    float n1 = y1 / fmaxf(sqrtf(ss1), 1e-12f);
    p1h[(u << 6) + lane] = f2bf(n0);
    p2h[(u << 6) + lane] = f2bf(n1);
    float d = n0 * n1;
    #pragma unroll
    for (int off = 1; off < 64; off <<= 1) d += __shfl_xor(d, off);
    if (lane == 0) diag[u] = d * 2.0f;
}

// ---------------------------------------------------------------------------
// MFMA LSE: one traversal of logits = 2 * A@B^T -> row & col exp-sum partials.
// ---------------------------------------------------------------------------
#define NCHUNK 25
#define TILES_PER_CHUNK 10
#define NWAVES (250 * NCHUNK)
__global__ __launch_bounds__(256) void lse_mfma(
    const ushort* __restrict__ Ah, const ushort* __restrict__ Bh,
    float* __restrict__ rowp, float* __restrict__ colp)
{
    int W = blockIdx.x * 4 + (threadIdx.x >> 6);
    if (W >= NWAVES) return;
    int lane = threadIdx.x & 63;
    int strip = W / NCHUNK;
    int chunk = W % NCHUNK;
    int i0 = strip * 32;
    int hl = lane >> 5;
    int l31 = lane & 31;

    const bf16x8* A8 = (const bf16x8*)Ah;
    const bf16x8* B8 = (const bf16x8*)Bh;

    bf16x8 afrag[4];
    #pragma unroll
    for (int m = 0; m < 4; ++m)
        afrag[m] = A8[(i0 + l31) * 8 + m * 2 + hl];

    float rowacc[16];
    #pragma unroll
    for (int r = 0; r < 16; ++r) rowacc[r] = 0.f;

    for (int tj = 0; tj < TILES_PER_CHUNK; ++tj) {
        int j0 = chunk * (TILES_PER_CHUNK * 32) + tj * 32;
        bf16x8 bfrag[4];
        #pragma unroll
        for (int m = 0; m < 4; ++m)
            bfrag[m] = B8[(j0 + l31) * 8 + m * 2 + hl];
        f32x16 acc;
        #pragma unroll
        for (int r = 0; r < 16; ++r) acc[r] = 0.f;
        #pragma unroll
        for (int m = 0; m < 4; ++m)
            acc = __builtin_amdgcn_mfma_f32_32x32x16_bf16(afrag[m], bfrag[m], acc, 0, 0, 0);
        float csum = 0.f;
        #pragma unroll
        for (int r = 0; r < 16; ++r) {
            float e = __expf(acc[r] * 2.0f);
            rowacc[r] += e;
            csum += e;
        }
        csum += __shfl_xor(csum, 32);
        if (lane < 32) colp[strip * 8000 + j0 + lane] = csum;
    }
    #pragma unroll
    for (int r = 0; r < 16; ++r) {
        float v = rowacc[r];
        #pragma unroll
        for (int off = 1; off < 32; off <<= 1) v += __shfl_xor(v, off);
        if (l31 == 0)
            rowp[chunk * 8000 + i0 + (r & 3) + 8 * (r >> 2) + 4 * hl] = v;
    }
}

// ---------------------------------------------------------------------------
// se_row[i] = sum_c rowp[c][i]; se_col[j] = sum_s colp[s][j]
// ---------------------------------------------------------------------------
__global__ __launch_bounds__(256) void reduce_partials(
    const float* __restrict__ rowp, const float* __restrict__ colp,
    float* __restrict__ se_row, float* __restrict__ se_col)
{
    int id = blockIdx.x * 256 + threadIdx.x;
    if (id < N_USERS) {
        float s = 0.f;
        for (int c = 0; c < NCHUNK; ++c) s += rowp[c * 8000 + id];
        se_row[id] = s;
    } else if (id < 2 * N_USERS) {
        int j = id - N_USERS;
        float s = 0.f;
        for (int st = 0; st < 250; ++st) s += colp[st * 8000 + j];
        se_col[j] = s;
    }
}

// ---------------------------------------------------------------------------
// loss = mean_i( 0.5*(log(se_row)+log(se_col)) - diag )
// ---------------------------------------------------------------------------
__global__ __launch_bounds__(256) void loss_kernel(
    const float* __restrict__ se_row, const float* __restrict__ se_col,
    const float* __restrict__ diag, float* __restrict__ out)
{
    __shared__ float red[256];
    int t = threadIdx.x;
    float s = 0.f;
    for (int i = t; i < N_USERS; i += 256)
        s += 0.5f * (logf(se_row[i]) + logf(se_col[i])) - diag[i];
    red[t] = s;
    __syncthreads();
    for (int w = 128; w > 0; w >>= 1) {
        if (t < w) red[t] += red[t + w];
        __syncthreads();
    }
    if (t == 0) out[0] = red[0] / (float)N_USERS;
}

extern "C" void kernel_launch(void* const* d_in, const int* in_sizes, int n_in,
                              void* d_out, int out_size, void* d_ws, size_t ws_size,
                              hipStream_t stream)
{
    const float* user_emb   = (const float*)d_in[0];
    const float* user_ui    = (const float*)d_in[1];
    const float* entity_emb = (const float*)d_in[2];
    const float* W1 = (const float*)d_in[3];
    const float* b1 = (const float*)d_in[4];
    const float* W2 = (const float*)d_in[5];
    const float* b2 = (const float*)d_in[6];
    const int* ui_index = (const int*)d_in[7];
    const int* ei_index = (const int*)d_in[8];

    float* ws = (float*)d_ws;
    // Layout (float units). Lifetimes stream-ordered; overlays noted.
    float* acc    = ws;                        // [0, 2,048,000) dead after combine_proj
    float* colp   = acc;                       //   overlay: lse col partials (2,000,000)
    float* se_row = ws + 2048000;              // 8,000
    float* se_col = se_row + 8000;             // 8,000
    float* diag   = se_col + 8000;             // 8,000  (ends 2,072,000)
    ushort* p1h = (ushort*)(ws + 2072000);     // 512,000 ushort -> [2,072,000, 2,328,000)
    ushort* p2h = (ushort*)(ws + 2328000);     // 512,000 ushort -> [2,328,000, 2,584,000)
    float* rowp = ws + 2584000;                // 200,000 -> ends 2,784,000
    int* cnt_u = (int*)(ws + 2784000);         // 4*250 = 1,000
    int* cnt_e = cnt_u + N_GROUPS * UBUCK;     // 4*500 = 2,000 (ends 2,787,000)
    int* bin_u = cnt_e + N_GROUPS * EBUCK;     // 4*250*1024 = 1,024,000 (ends 3,811,000)
    int* bin_e = bin_u + N_GROUPS * UBUCK * UCAP; // 4*500*640 = 1,280,000 (ends 5,091,000)
    ushort* ueh = (ushort*)(ws + 5091000);     // 512,000 ushort (256,000 f)
    ushort* eeh = (ushort*)(ws + 5347000);     // 2,048,000 ushort (ends 6,371,000)
    ushort* ebufh = (ushort*)(ws + 6371000);   // nG * 2,048,000 ushort

    const size_t BASE_F = 6371000;
    int nG = 1;
    if (ws_size >= (BASE_F + 4 * 1024000) * 4) nG = 4;       // 41.9 MB
    else if (ws_size >= (BASE_F + 2 * 1024000) * 4) nG = 2;  // 33.7 MB

    float* out_user = (float*)d_out;           // 512,000
    float* out_loss = out_user + 512000;       // 1

    dim3 b256(256);

    hipMemsetAsync(cnt_u, 0, (size_t)N_GROUPS * (UBUCK + EBUCK) * 4, stream);
    convert_tables<<<2500, b256, 0, stream>>>(user_emb, entity_emb, ueh, eeh);
    bin_edges<<<dim3((N_EDGES + BIN_CHUNK - 1) / BIN_CHUNK, N_GROUPS), b256, 0, stream>>>(
        ui_index, ei_index, cnt_u, cnt_e, bin_u, bin_e);

    for (int gbase = 0; gbase < N_GROUPS; gbase += nG) {
        agg_entity_b<<<dim3(EBUCK, nG), b256, 0, stream>>>(
            cnt_e, bin_e, ueh, ebufh, gbase);
        agg_user_b<<<dim3(UBUCK, nG), b256, 0, stream>>>(
            cnt_u, bin_u, eeh, ebufh, acc, gbase);
    }

    combine_proj<<<N_USERS / 4, b256, 0, stream>>>(
        acc, user_ui, user_emb, W1, b1, W2, b2,
        out_user, p1h, p2h, diag);

    lse_mfma<<<(NWAVES + 3) / 4, b256, 0, stream>>>(p1h, p2h, rowp, colp);
    reduce_partials<<<(2 * N_USERS + 255) / 256, b256, 0, stream>>>(
        rowp, colp, se_row, se_col);
    loss_kernel<<<1, b256, 0, stream>>>(se_row, se_col, diag, out_loss);
}

// Round 11
// 182.142 us; speedup vs baseline: 5.1993x; 1.0674x over previous
//
#include <hip/hip_runtime.h>
#include <hip/hip_bf16.h>
#include <math.h>

#define N_USERS 8000
#define N_ENTITIES 32000
#define EMB 64
#define N_GROUPS 4
#define N_EDGES 200000

// bucketed adjacency (finer buckets for occupancy; XCD-pair group affinity)
#define UBUCK 500            // 8000 users  / 16 per bucket (mean 400 edges)
#define EBUCK 1000           // 32000 ents  / 32 per bucket (mean 200 edges)
#define UCAP 640             // mean 400, +12 sigma
#define ECAP 384             // mean 200, +13 sigma
#define BIN_CHUNK 2048

typedef __attribute__((ext_vector_type(8))) __bf16 bf16x8;
typedef __attribute__((ext_vector_type(16))) float f32x16;

static __device__ __forceinline__ unsigned short f2bf(float f) {
    union { float f; unsigned int i; } x; x.f = f;
    return (unsigned short)((x.i + 0x7FFF + ((x.i >> 16) & 1)) >> 16);
}
static __device__ __forceinline__ float u2f(unsigned int u) {
    union { unsigned int i; float f; } x; x.i = u; return x.f;
}

// ---------------------------------------------------------------------------
// Convert user_emb / entity_emb to bf16 tables.
// ---------------------------------------------------------------------------
__global__ __launch_bounds__(256) void convert_tables(
    const float* __restrict__ ue, const float* __restrict__ ee,
    ushort* __restrict__ ueh, ushort* __restrict__ eeh)
{
    int i4 = blockIdx.x * 256 + threadIdx.x;   // float4 units
    if (i4 < 128000) {
        float4 v = ((const float4*)ue)[i4];
        ushort4 o; o.x = f2bf(v.x); o.y = f2bf(v.y); o.z = f2bf(v.z); o.w = f2bf(v.w);
        ((ushort4*)ueh)[i4] = o;
    } else if (i4 < 640000) {
        int j = i4 - 128000;
        float4 v = ((const float4*)ee)[j];
        ushort4 o; o.x = f2bf(v.x); o.y = f2bf(v.y); o.z = f2bf(v.z); o.w = f2bf(v.w);
        ((ushort4*)eeh)[j] = o;
    }
}

// ---------------------------------------------------------------------------
// Destination-bucketed binning, both directions, per group.
// word (user dir):  (u & 15) | (v << 4)   bucket = u >> 4   (500 buckets)
// word (ent  dir):  (v & 31) | (u << 5)   bucket = v >> 5   (1000 buckets)
// Only int atomics: LDS histogram + one global atomicAdd per (block,bucket).
// ---------------------------------------------------------------------------
__global__ __launch_bounds__(256) void bin_edges(
    const int* __restrict__ ui_index, const int* __restrict__ ei_index,
    int* __restrict__ cnt_u, int* __restrict__ cnt_e,
    int* __restrict__ bin_u, int* __restrict__ bin_e)
{
    int g = blockIdx.y;
    const int* ui = ui_index + (size_t)g * N_EDGES;
    const int* ei = ei_index + (size_t)g * N_EDGES;
    __shared__ int hU[UBUCK], hE[EBUCK], bU[UBUCK], bE[EBUCK];
    int t = threadIdx.x;
    for (int i = t; i < UBUCK; i += 256) hU[i] = 0;
    for (int i = t; i < EBUCK; i += 256) hE[i] = 0;
    __syncthreads();
    int e0 = blockIdx.x * BIN_CHUNK;
    int us[8], vs[8];
    #pragma unroll
    for (int i = 0; i < 8; ++i) {
        int e = e0 + i * 256 + t;
        bool ok = e < N_EDGES;
        us[i] = ok ? ui[e] : -1;
        vs[i] = ok ? ei[e] : 0;
        if (ok) {
            atomicAdd(&hU[us[i] >> 4], 1);
            atomicAdd(&hE[vs[i] >> 5], 1);
        }
    }
    __syncthreads();
    for (int i = t; i < UBUCK; i += 256) {
        int c = hU[i];
        bU[i] = c ? atomicAdd(&cnt_u[g * UBUCK + i], c) : 0;
        hU[i] = 0;
    }
    for (int i = t; i < EBUCK; i += 256) {
        int c = hE[i];
        bE[i] = c ? atomicAdd(&cnt_e[g * EBUCK + i], c) : 0;
        hE[i] = 0;
    }
    __syncthreads();
    #pragma unroll
    for (int i = 0; i < 8; ++i) {
        if (us[i] >= 0) {
            int bu = us[i] >> 4;
            int s = atomicAdd(&hU[bu], 1) + bU[bu];
            if (s < UCAP)
                bin_u[((size_t)g * UBUCK + bu) * UCAP + s] = (us[i] & 15) | (vs[i] << 4);
            int be = vs[i] >> 5;
            int s2 = atomicAdd(&hE[be], 1) + bE[be];
            if (s2 < ECAP)
                bin_e[((size_t)g * EBUCK + be) * ECAP + s2] = (vs[i] & 31) | (us[i] << 5);
        }
    }
}

// ---------------------------------------------------------------------------
// group/bucket mapping: affin -> flat grid with XCD-pair group affinity
// (blocks with blockIdx%8 in {2g, 2g+1} process group g, so each XCD pair's
// 8 MB of L2 holds exactly eeh + that group's ebufh).
// ---------------------------------------------------------------------------
static __device__ __forceinline__ void map_gb(int gbase, int affin, int& g, int& b)
{
    if (affin) {
        int bid = blockIdx.x;
        int xcd = bid & 7;
        g = xcd >> 1;
        b = ((bid >> 3) << 1) | (xcd & 1);
    } else {
        g = gbase + blockIdx.y;
        b = blockIdx.x;
    }
}

// ---------------------------------------------------------------------------
// Entity hop0, bucketed: counting-sort the bucket's entries in LDS (int
// atomics only), then per destination row: quad-slot register accumulation
// (4 edge slots x 16 dim-lanes, uint2 = 4 bf16 dims/lane), cross-slot
// shfl_xor reduce, l2norm, bf16 store.
// ---------------------------------------------------------------------------
__global__ __launch_bounds__(256) void agg_entity_b(
    const int* __restrict__ cnt_e, const int* __restrict__ bin_e,
    const ushort* __restrict__ ueh, ushort* __restrict__ ebufh,
    int gbase, int affin)
{
    int g, b;
    map_gb(gbase, affin, g, b);
    int gz = g - gbase;
    __shared__ int wds[ECAP];
    __shared__ int srt[ECAP];
    __shared__ int cnt[32];
    __shared__ int ptr[33];
    __shared__ int cur[32];
    int t = threadIdx.x;
    int count = min(cnt_e[g * EBUCK + b], ECAP);
    const int* bin = bin_e + ((size_t)g * EBUCK + b) * ECAP;
    if (t < 32) cnt[t] = 0;
    __syncthreads();
    for (int i = t; i < count; i += 256) {
        int w_ = bin[i];
        wds[i] = w_;
        atomicAdd(&cnt[w_ & 31], 1);
    }
    __syncthreads();
    if (t == 0) {
        int run = 0;
        for (int i = 0; i < 32; ++i) { ptr[i] = run; run += cnt[i]; }
        ptr[32] = run;
    }
    __syncthreads();
    if (t < 32) cur[t] = ptr[t];
    __syncthreads();
    for (int i = t; i < count; i += 256) {
        int w_ = wds[i];
        int pos = atomicAdd(&cur[w_ & 31], 1);
        srt[pos] = w_ >> 5;
    }
    __syncthreads();
    int wv = t >> 6, lane = t & 63, q = lane >> 4, d16 = lane & 15;
    for (int r = wv; r < 32; r += 4) {
        int start = ptr[r], end = ptr[r + 1];
        float a0 = 0.f, a1 = 0.f, a2 = 0.f, a3 = 0.f;
        for (int base = start; base < end; base += 4) {
            int idx = base + q;
            int src = idx < end ? srt[idx] : -1;
            unsigned sidx = src >= 0 ? (unsigned)src : 0u;
            uint2 r2 = *(const uint2*)(ueh + (sidx << 6) + (d16 << 2));
            if (src < 0) { r2.x = 0u; r2.y = 0u; }
            a0 += u2f(r2.x << 16);
            a1 += u2f(r2.x & 0xFFFF0000u);
            a2 += u2f(r2.y << 16);
            a3 += u2f(r2.y & 0xFFFF0000u);
        }
        a0 += __shfl_xor(a0, 16); a0 += __shfl_xor(a0, 32);
        a1 += __shfl_xor(a1, 16); a1 += __shfl_xor(a1, 32);
        a2 += __shfl_xor(a2, 16); a2 += __shfl_xor(a2, 32);
        a3 += __shfl_xor(a3, 16); a3 += __shfl_xor(a3, 32);
        float ss = a0 * a0 + a1 * a1 + a2 * a2 + a3 * a3;
        #pragma unroll
        for (int off = 1; off < 16; off <<= 1) ss += __shfl_xor(ss, off);
        float inv = 1.0f / fmaxf(sqrtf(ss), 1e-12f);
        if (lane < 16) {
            ushort4 o;
            o.x = f2bf(a0 * inv); o.y = f2bf(a1 * inv);
            o.z = f2bf(a2 * inv); o.w = f2bf(a3 * inv);
            *(ushort4*)(ebufh + (size_t)gz * N_ENTITIES * EMB
                        + (((size_t)b * 32 + r) << 6) + (d16 << 2)) = o;
        }
    }
}

// ---------------------------------------------------------------------------
// User hop0+hop1 fused, bucketed: same counting-sort, then per row gather
// BOTH eeh and ebufh rows per edge slot; acc = norm(A) + norm(B).
// ---------------------------------------------------------------------------
__global__ __launch_bounds__(256) void agg_user_b(
    const int* __restrict__ cnt_u, const int* __restrict__ bin_u,
    const ushort* __restrict__ eeh, const ushort* __restrict__ ebufh,
    float* __restrict__ acc, int gbase, int affin)
{
    int g, b;
    map_gb(gbase, affin, g, b);
    int gz = g - gbase;
    __shared__ int wds[UCAP];
    __shared__ int srt[UCAP];
    __shared__ int cnt[16];
    __shared__ int ptr[17];
    __shared__ int cur[16];
    int t = threadIdx.x;
    int count = min(cnt_u[g * UBUCK + b], UCAP);
    const int* bin = bin_u + ((size_t)g * UBUCK + b) * UCAP;
    const ushort* tabB = ebufh + (size_t)gz * N_ENTITIES * EMB;
    if (t < 16) cnt[t] = 0;
    __syncthreads();
    for (int i = t; i < count; i += 256) {
        int w_ = bin[i];
        wds[i] = w_;
        atomicAdd(&cnt[w_ & 15], 1);
    }
    __syncthreads();
    if (t == 0) {
        int run = 0;
        for (int i = 0; i < 16; ++i) { ptr[i] = run; run += cnt[i]; }
        ptr[16] = run;
    }
    __syncthreads();
    if (t < 16) cur[t] = ptr[t];
    __syncthreads();
    for (int i = t; i < count; i += 256) {
        int w_ = wds[i];
        int pos = atomicAdd(&cur[w_ & 15], 1);
        srt[pos] = w_ >> 4;
    }
    __syncthreads();
    int wv = t >> 6, lane = t & 63, q = lane >> 4, d16 = lane & 15;
    for (int r = wv; r < 16; r += 4) {
        int start = ptr[r], end = ptr[r + 1];
        float a0 = 0.f, a1 = 0.f, a2 = 0.f, a3 = 0.f;
        float b0 = 0.f, b1_ = 0.f, b2_ = 0.f, b3 = 0.f;
        for (int base = start; base < end; base += 4) {
            int idx = base + q;
            int src = idx < end ? srt[idx] : -1;
            unsigned sidx = src >= 0 ? (unsigned)src : 0u;
            unsigned off = (sidx << 6) + (d16 << 2);
            uint2 ra = *(const uint2*)(eeh + off);
            uint2 rb = *(const uint2*)(tabB + off);
            if (src < 0) { ra.x = 0u; ra.y = 0u; rb.x = 0u; rb.y = 0u; }
            a0 += u2f(ra.x << 16);
            a1 += u2f(ra.x & 0xFFFF0000u);
            a2 += u2f(ra.y << 16);
            a3 += u2f(ra.y & 0xFFFF0000u);
            b0  += u2f(rb.x << 16);
            b1_ += u2f(rb.x & 0xFFFF0000u);
            b2_ += u2f(rb.y << 16);
            b3  += u2f(rb.y & 0xFFFF0000u);
        }
        a0 += __shfl_xor(a0, 16); a0 += __shfl_xor(a0, 32);
        a1 += __shfl_xor(a1, 16); a1 += __shfl_xor(a1, 32);
        a2 += __shfl_xor(a2, 16); a2 += __shfl_xor(a2, 32);
        a3 += __shfl_xor(a3, 16); a3 += __shfl_xor(a3, 32);
        b0  += __shfl_xor(b0, 16);  b0  += __shfl_xor(b0, 32);
        b1_ += __shfl_xor(b1_, 16); b1_ += __shfl_xor(b1_, 32);
        b2_ += __shfl_xor(b2_, 16); b2_ += __shfl_xor(b2_, 32);
        b3  += __shfl_xor(b3, 16);  b3  += __shfl_xor(b3, 32);
        float ssA = a0 * a0 + a1 * a1 + a2 * a2 + a3 * a3;
        float ssB = b0 * b0 + b1_ * b1_ + b2_ * b2_ + b3 * b3;
        #pragma unroll
        for (int off = 1; off < 16; off <<= 1) {
            ssA += __shfl_xor(ssA, off);
            ssB += __shfl_xor(ssB, off);
        }
        float invA = 1.0f / fmaxf(sqrtf(ssA), 1e-12f);
        float invB = 1.0f / fmaxf(sqrtf(ssB), 1e-12f);
        if (lane < 16) {
            float4 o;
            o.x = a0 * invA + b0 * invB;
            o.y = a1 * invA + b1_ * invB;
            o.z = a2 * invA + b2_ * invB;
            o.w = a3 * invA + b3 * invB;
            *(float4*)(acc + (size_t)g * N_USERS * EMB
                       + (((size_t)b * 16 + r) << 6) + (d16 << 2)) = o;
        }
    }
}

// ---------------------------------------------------------------------------
// Fused: attention-combine -> out_user; proj+normalize of (uie, out_user)
// -> bf16 p1h/p2h; diag = 2*dot(n0,n1).
// ---------------------------------------------------------------------------
__global__ __launch_bounds__(256) void combine_proj(
    const float* __restrict__ acc, const float* __restrict__ uie,
    const float* __restrict__ uemb,
    const float* __restrict__ W1, const float* __restrict__ b1,
    const float* __restrict__ W2, const float* __restrict__ b2,
    float* __restrict__ out_user,
    ushort* __restrict__ p1h, ushort* __restrict__ p2h,
    float* __restrict__ diag)
{
    __shared__ float W1s[EMB * EMB];
    __shared__ float W2s[EMB * EMB];
    __shared__ float zs[4][2][EMB];
    __shared__ float hs[4][2][EMB];
    int t = threadIdx.x;
    for (int i = t; i < EMB * EMB; i += 256) { W1s[i] = W1[i]; W2s[i] = W2[i]; }
    int w = t >> 6, lane = t & 63;
    int u = blockIdx.x * 4 + w;

    float ue = uie[(u << 6) + lane];
    float av[N_GROUPS], s[N_GROUPS];
    #pragma unroll
    for (int g = 0; g < N_GROUPS; ++g) {
        av[g] = acc[(size_t)g * N_USERS * EMB + (u << 6) + lane];
        float p = av[g] * ue;
        #pragma unroll
        for (int off = 1; off < 64; off <<= 1) p += __shfl_xor(p, off);
        s[g] = p;
    }
    float m = fmaxf(fmaxf(s[0], s[1]), fmaxf(s[2], s[3]));
    float att[N_GROUPS], tot = 0.f;
    #pragma unroll
    for (int g = 0; g < N_GROUPS; ++g) { att[g] = __expf(s[g] - m); tot += att[g]; }
    float inv = 1.0f / tot;
    float o = uemb[(u << 6) + lane];
    #pragma unroll
    for (int g = 0; g < N_GROUPS; ++g) o += att[g] * inv * av[g];
    out_user[(u << 6) + lane] = o;

    zs[w][0][lane] = ue;
    zs[w][1][lane] = o;
    __syncthreads();
    float h0 = b1[lane], h1 = b1[lane];
    #pragma unroll
    for (int k = 0; k < EMB; ++k) {
        float w1 = W1s[k * EMB + lane];
        h0 = fmaf(zs[w][0][k], w1, h0);
        h1 = fmaf(zs[w][1][k], w1, h1);
    }
    h0 = h0 > 0.f ? h0 : expm1f(h0);
    h1 = h1 > 0.f ? h1 : expm1f(h1);
    hs[w][0][lane] = h0;
    hs[w][1][lane] = h1;
    __syncthreads();
    float y0 = b2[lane], y1 = b2[lane];
    #pragma unroll
    for (int k = 0; k < EMB; ++k) {
        float w2 = W2s[k * EMB + lane];
        y0 = fmaf(hs[w][0][k], w2, y0);
        y1 = fmaf(hs[w][1][k], w2, y1);
    }
    float ss0 = y0 * y0, ss1 = y1 * y1;
    #pragma unroll
    for (int off = 1; off < 64; off <<= 1) {
        ss0 += __shfl_xor(ss0, off);
        ss1 += __shfl_xor(ss1, off);
    }
    float n0 = y0 / fmaxf(sqrtf(ss0), 1e-12f);
    float n1 = y1 / fmaxf(sqrtf(ss1), 1e-12f);
    p1h[(u << 6) + lane] = f2bf(n0);
    p2h[(u << 6) + lane] = f2bf(n1);
    float d = n0 * n1;
    #pragma unroll
    for (int off = 1; off < 64; off <<= 1) d += __shfl_xor(d, off);
    if (lane == 0) diag[u] = d * 2.0f;
}

// ---------------------------------------------------------------------------
// MFMA LSE: one traversal of logits = 2 * A@B^T -> row & col exp-sum partials.
// ---------------------------------------------------------------------------
#define NCHUNK 25
#define TILES_PER_CHUNK 10
#define NWAVES (250 * NCHUNK)
__global__ __launch_bounds__(256) void lse_mfma(
    const ushort* __restrict__ Ah, const ushort* __restrict__ Bh,
    float* __restrict__ rowp, float* __restrict__ colp)
{
    int W = blockIdx.x * 4 + (threadIdx.x >> 6);
    if (W >= NWAVES) return;
    int lane = threadIdx.x & 63;
    int strip = W / NCHUNK;
    int chunk = W % NCHUNK;
    int i0 = strip * 32;
    int hl = lane >> 5;
    int l31 = lane & 31;

    const bf16x8* A8 = (const bf16x8*)Ah;
    const bf16x8* B8 = (const bf16x8*)Bh;

    bf16x8 afrag[4];
    #pragma unroll
    for (int m = 0; m < 4; ++m)
        afrag[m] = A8[(i0 + l31) * 8 + m * 2 + hl];

    float rowacc[16];
    #pragma unroll
    for (int r = 0; r < 16; ++r) rowacc[r] = 0.f;

    for (int tj = 0; tj < TILES_PER_CHUNK; ++tj) {
        int j0 = chunk * (TILES_PER_CHUNK * 32) + tj * 32;
        bf16x8 bfrag[4];
        #pragma unroll
        for (int m = 0; m < 4; ++m)
            bfrag[m] = B8[(j0 + l31) * 8 + m * 2 + hl];
        f32x16 acc;
        #pragma unroll
        for (int r = 0; r < 16; ++r) acc[r] = 0.f;
        #pragma unroll
        for (int m = 0; m < 4; ++m)
            acc = __builtin_amdgcn_mfma_f32_32x32x16_bf16(afrag[m], bfrag[m], acc, 0, 0, 0);
        float csum = 0.f;
        #pragma unroll
        for (int r = 0; r < 16; ++r) {
            float e = __expf(acc[r] * 2.0f);
            rowacc[r] += e;
            csum += e;
        }
        csum += __shfl_xor(csum, 32);
        if (lane < 32) colp[strip * 8000 + j0 + lane] = csum;
    }
    #pragma unroll
    for (int r = 0; r < 16; ++r) {
        float v = rowacc[r];
        #pragma unroll
        for (int off = 1; off < 32; off <<= 1) v += __shfl_xor(v, off);
        if (l31 == 0)
            rowp[chunk * 8000 + i0 + (r & 3) + 8 * (r >> 2) + 4 * hl] = v;
    }
}

// ---------------------------------------------------------------------------
// se_row[i] = sum_c rowp[c][i]; se_col[j] = sum_s colp[s][j]
// ---------------------------------------------------------------------------
__global__ __launch_bounds__(256) void reduce_partials(
    const float* __restrict__ rowp, const float* __restrict__ colp,
    float* __restrict__ se_row, float* __restrict__ se_col)
{
    int id = blockIdx.x * 256 + threadIdx.x;
    if (id < N_USERS) {
        float s = 0.f;
        for (int c = 0; c < NCHUNK; ++c) s += rowp[c * 8000 + id];
        se_row[id] = s;
    } else if (id < 2 * N_USERS) {
        int j = id - N_USERS;
        float s = 0.f;
        for (int st = 0; st < 250; ++st) s += colp[st * 8000 + j];
        se_col[j] = s;
    }
}

// ---------------------------------------------------------------------------
// loss = mean_i( 0.5*(log(se_row)+log(se_col)) - diag )
// ---------------------------------------------------------------------------
__global__ __launch_bounds__(256) void loss_kernel(
    const float* __restrict__ se_row, const float* __restrict__ se_col,
    const float* __restrict__ diag, float* __restrict__ out)
{
    __shared__ float red[256];
    int t = threadIdx.x;
    float s = 0.f;
    for (int i = t; i < N_USERS; i += 256)
        s += 0.5f * (logf(se_row[i]) + logf(se_col[i])) - diag[i];
    red[t] = s;
    __syncthreads();
    for (int w = 128; w > 0; w >>= 1) {
        if (t < w) red[t] += red[t + w];
        __syncthreads();
    }
    if (t == 0) out[0] = red[0] / (float)N_USERS;
}

extern "C" void kernel_launch(void* const* d_in, const int* in_sizes, int n_in,
                              void* d_out, int out_size, void* d_ws, size_t ws_size,
                              hipStream_t stream)
{
    const float* user_emb   = (const float*)d_in[0];
    const float* user_ui    = (const float*)d_in[1];
    const float* entity_emb = (const float*)d_in[2];
    const float* W1 = (const float*)d_in[3];
    const float* b1 = (const float*)d_in[4];
    const float* W2 = (const float*)d_in[5];
    const float* b2 = (const float*)d_in[6];
    const int* ui_index = (const int*)d_in[7];
    const int* ei_index = (const int*)d_in[8];

    float* ws = (float*)d_ws;
    // Layout (float units). Lifetimes stream-ordered; overlays noted.
    float* acc    = ws;                        // [0, 2,048,000) dead after combine_proj
    float* colp   = acc;                       //   overlay: lse col partials (2,000,000)
    float* se_row = ws + 2048000;              // 8,000
    float* se_col = se_row + 8000;             // 8,000
    float* diag   = se_col + 8000;             // 8,000  (ends 2,072,000)
    ushort* p1h = (ushort*)(ws + 2072000);     // 512,000 ushort
    ushort* p2h = (ushort*)(ws + 2328000);     // 512,000 ushort
    float* rowp = ws + 2584000;                // 200,000 -> ends 2,784,000
    int* cnt_u = (int*)(ws + 2784000);         // 4*500 = 2,000
    int* cnt_e = cnt_u + N_GROUPS * UBUCK;     // 4*1000 = 4,000 (ends 2,790,000)
    int* bin_u = cnt_e + N_GROUPS * EBUCK;     // 4*500*640 = 1,280,000 (ends 4,070,000)
    int* bin_e = bin_u + N_GROUPS * UBUCK * UCAP; // 4*1000*384 = 1,536,000 (ends 5,606,000)
    ushort* ueh = (ushort*)(ws + 5606000);     // 512,000 ushort (256,000 f)
    ushort* eeh = (ushort*)(ws + 5862000);     // 2,048,000 ushort (ends 6,886,000)
    ushort* ebufh = (ushort*)(ws + 6886000);   // nG * 2,048,000 ushort

    const size_t BASE_F = 6886000;
    int nG = 1;
    if (ws_size >= (BASE_F + 4 * 1024000) * 4) nG = 4;       // 44.0 MB
    else if (ws_size >= (BASE_F + 2 * 1024000) * 4) nG = 2;  // 35.8 MB

    float* out_user = (float*)d_out;           // 512,000
    float* out_loss = out_user + 512000;       // 1

    dim3 b256(256);

    hipMemsetAsync(cnt_u, 0, (size_t)N_GROUPS * (UBUCK + EBUCK) * 4, stream);
    convert_tables<<<2500, b256, 0, stream>>>(user_emb, entity_emb, ueh, eeh);
    bin_edges<<<dim3((N_EDGES + BIN_CHUNK - 1) / BIN_CHUNK, N_GROUPS), b256, 0, stream>>>(
        ui_index, ei_index, cnt_u, cnt_e, bin_u, bin_e);

    if (nG == 4) {
        // flat grids with XCD-pair group affinity
        agg_entity_b<<<EBUCK * 4, b256, 0, stream>>>(
            cnt_e, bin_e, ueh, ebufh, 0, 1);
        agg_user_b<<<UBUCK * 4, b256, 0, stream>>>(
            cnt_u, bin_u, eeh, ebufh, acc, 0, 1);
    } else {
        for (int gbase = 0; gbase < N_GROUPS; gbase += nG) {
            agg_entity_b<<<dim3(EBUCK, nG), b256, 0, stream>>>(
                cnt_e, bin_e, ueh, ebufh, gbase, 0);
            agg_user_b<<<dim3(UBUCK, nG), b256, 0, stream>>>(
                cnt_u, bin_u, eeh, ebufh, acc, gbase, 0);
        }
    }

    combine_proj<<<N_USERS / 4, b256, 0, stream>>>(
        acc, user_ui, user_emb, W1, b1, W2, b2,
        out_user, p1h, p2h, diag);

    lse_mfma<<<(NWAVES + 3) / 4, b256, 0, stream>>>(p1h, p2h, rowp, colp);
    reduce_partials<<<(2 * N_USERS + 255) / 256, b256, 0, stream>>>(
        rowp, colp, se_row, se_col);
    loss_kernel<<<1, b256, 0, stream>>>(se_row, se_col, diag, out_loss);
}